// Round 4
// baseline (1018.531 us; speedup 1.0000x reference)
//
#include <hip/hip_runtime.h>
#include <hip/hip_fp16.h>

// Sinkhorn, 64 x 1024 x 1024 fp32, 20 iterations.
//
// K = exp(-C/eps); u = 1/(K v); v = 1/(K^T u); out = u_i K_ij v_j.
//
// Round-3 counters: 6.3 GB of L2-miss traffic (ideal ~1 GB) at the fabric
// ceiling => BW-bound on AMPLIFIED traffic. Amplifiers: (1) 21M device-scope
// csum atomicAdds (~2.7 GB of coherence-point RMW + serialization),
// (2) __threadfence in the grid barrier (buffer_wbl2/inv) flushing per-XCD
// L2 20x, forcing K8 re-fetch from L3/HBM every sweep.
//
// This round:
//  - csum atomics -> per-block partial vectors, ping-pong 2 slots, written
//    with relaxed AGENT-scope coherent stores (4 KB/block). Next phase,
//    each block re-reduces its batch's 16 partials (64 KB coherent reads),
//    inverts, broadcasts v via LDS. No atomics in the data path.
//  - fence-free grid barrier: all cross-block data moves via agent-scope
//    coherent ops (L2-bypass), so no threadfence / L2 invalidation at all.
//    __syncthreads drains vmcnt before arrival (stores complete at the
//    coherence point); explicit vmcnt(0) orders master resets before the
//    generation release. K8 stays (partially) resident in per-XCD L2.
//  - phase structure, fp8 sweeps (iters 2..19), fp16 iter 20 + final
//    product unchanged from round 3.
// Falls back to the round-2 multi-kernel path if occupancy check fails,
// and to the all-fp32 path if ws is too small.

#define BATCH 64
#define N 1024
#define NITERS 20
#define RPB 64                   // rows per block
#define BPB 16                   // blocks per batch
#define NBLK (BATCH * BPB)       // 1024 blocks
#define THREADS 256
#define NU2 (N / 4)              // uint2 (4 halves) per fp16 row
#define NU4 (N / 8)              // uint4 (8 halves) per fp16 row
#define NU4F8 (N / 16)           // uint4 (16 fp8) per fp8 row
#define NGRP 64                  // barrier groups
#define BAR_WORDS 128            // grp[64], master, gen, padding
#define PART_ELEMS ((size_t)2 * BATCH * BPB * N)   // 2 ping-pong slots
#define CSUM_FB_ELEMS ((size_t)NITERS * BATCH * N) // fallback path only

typedef float f32x2 __attribute__((ext_vector_type(2)));

// ---------- fp16 pack/unpack helpers ----------
union H2U { __half2 h; unsigned u; };

__device__ __forceinline__ float4 h4_to_f4(uint2 r) {
    H2U a, b;
    a.u = r.x; b.u = r.y;
    float2 fa = __half22float2(a.h);
    float2 fb = __half22float2(b.h);
    return make_float4(fa.x, fa.y, fb.x, fb.y);
}

__device__ __forceinline__ void h8_unpack(uint4 r, float* f) {
    H2U a, b, c, d;
    a.u = r.x; b.u = r.y; c.u = r.z; d.u = r.w;
    float2 fa = __half22float2(a.h), fb = __half22float2(b.h);
    float2 fc = __half22float2(c.h), fd = __half22float2(d.h);
    f[0] = fa.x; f[1] = fa.y; f[2] = fb.x; f[3] = fb.y;
    f[4] = fc.x; f[5] = fc.y; f[6] = fd.x; f[7] = fd.y;
}

__device__ __forceinline__ uint4 h8_pack(const float* f) {
    H2U a, b, c, d;
    a.h = __float22half2_rn(make_float2(f[0], f[1]));
    b.h = __float22half2_rn(make_float2(f[2], f[3]));
    c.h = __float22half2_rn(make_float2(f[4], f[5]));
    d.h = __float22half2_rn(make_float2(f[6], f[7]));
    uint4 r; r.x = a.u; r.y = b.u; r.z = c.u; r.w = d.u;
    return r;
}

// ---------- fp8 (OCP e4m3) pack/unpack via gfx950 HW cvt ----------
__device__ __forceinline__ uint4 pack_fp8_16(const float* k) {
    uint4 r;
    int a;
    a = __builtin_amdgcn_cvt_pk_fp8_f32(k[0],  k[1],  0, false);
    a = __builtin_amdgcn_cvt_pk_fp8_f32(k[2],  k[3],  a, true);
    r.x = (unsigned)a;
    a = __builtin_amdgcn_cvt_pk_fp8_f32(k[4],  k[5],  0, false);
    a = __builtin_amdgcn_cvt_pk_fp8_f32(k[6],  k[7],  a, true);
    r.y = (unsigned)a;
    a = __builtin_amdgcn_cvt_pk_fp8_f32(k[8],  k[9],  0, false);
    a = __builtin_amdgcn_cvt_pk_fp8_f32(k[10], k[11], a, true);
    r.z = (unsigned)a;
    a = __builtin_amdgcn_cvt_pk_fp8_f32(k[12], k[13], 0, false);
    a = __builtin_amdgcn_cvt_pk_fp8_f32(k[14], k[15], a, true);
    r.w = (unsigned)a;
    return r;
}

__device__ __forceinline__ void unpack_fp8_16(uint4 r, float* f) {
    f32x2 p;
    p = __builtin_amdgcn_cvt_pk_f32_fp8((int)r.x, false); f[0]  = p.x; f[1]  = p.y;
    p = __builtin_amdgcn_cvt_pk_f32_fp8((int)r.x, true);  f[2]  = p.x; f[3]  = p.y;
    p = __builtin_amdgcn_cvt_pk_f32_fp8((int)r.y, false); f[4]  = p.x; f[5]  = p.y;
    p = __builtin_amdgcn_cvt_pk_f32_fp8((int)r.y, true);  f[6]  = p.x; f[7]  = p.y;
    p = __builtin_amdgcn_cvt_pk_f32_fp8((int)r.z, false); f[8]  = p.x; f[9]  = p.y;
    p = __builtin_amdgcn_cvt_pk_f32_fp8((int)r.z, true);  f[10] = p.x; f[11] = p.y;
    p = __builtin_amdgcn_cvt_pk_f32_fp8((int)r.w, false); f[12] = p.x; f[13] = p.y;
    p = __builtin_amdgcn_cvt_pk_f32_fp8((int)r.w, true);  f[14] = p.x; f[15] = p.y;
}

// ---------- coherent (agent-scope, L2-bypass) load/store ----------
__device__ __forceinline__ float cload(const float* p) {
    return __hip_atomic_load((float*)p, __ATOMIC_RELAXED, __HIP_MEMORY_SCOPE_AGENT);
}
__device__ __forceinline__ void cstore(float* p, float v) {
    __hip_atomic_store(p, v, __ATOMIC_RELAXED, __HIP_MEMORY_SCOPE_AGENT);
}

// ---------- generic zero ----------
__global__ __launch_bounds__(THREADS) void sk_zero(float* __restrict__ buf,
                                                   int total) {
    const int i = blockIdx.x * THREADS + threadIdx.x;
    if (i < total) buf[i] = 0.0f;
}

// ---------- fence-free hierarchical grid barrier ----------
// bar layout: grp[NGRP], master at [NGRP], gen at [NGRP+1]. All zeroed.
// Correctness relies on ALL cross-block data moving via agent-scope
// coherent ops: __syncthreads drains each thread's vmcnt (stores ack'd at
// the coherence point) before lane 0 arrives. No L2 flush/invalidate.
__device__ __forceinline__ void gbar(unsigned* __restrict__ bar,
                                     unsigned& gencount) {
    __syncthreads();  // compiler emits s_waitcnt vmcnt(0) before s_barrier
    if (threadIdx.x == 0) {
        asm volatile("" ::: "memory");
        unsigned* grp    = bar;
        unsigned* master = bar + NGRP;
        unsigned* gen    = bar + NGRP + 1;
        const unsigned gid = blockIdx.x & (NGRP - 1);
        if (__hip_atomic_fetch_add(&grp[gid], 1u, __ATOMIC_RELAXED,
                                   __HIP_MEMORY_SCOPE_AGENT) == (NBLK / NGRP) - 1u) {
            if (__hip_atomic_fetch_add(master, 1u, __ATOMIC_RELAXED,
                                       __HIP_MEMORY_SCOPE_AGENT) == NGRP - 1u) {
                #pragma unroll
                for (int i = 0; i < NGRP; ++i)
                    __hip_atomic_store(&grp[i], 0u, __ATOMIC_RELAXED,
                                       __HIP_MEMORY_SCOPE_AGENT);
                __hip_atomic_store(master, 0u, __ATOMIC_RELAXED,
                                   __HIP_MEMORY_SCOPE_AGENT);
                // order resets before the generation release
                asm volatile("s_waitcnt vmcnt(0)" ::: "memory");
                __hip_atomic_fetch_add(gen, 1u, __ATOMIC_RELAXED,
                                       __HIP_MEMORY_SCOPE_AGENT);
            }
        }
        while (__hip_atomic_load(gen, __ATOMIC_RELAXED,
                                 __HIP_MEMORY_SCOPE_AGENT) == gencount)
            __builtin_amdgcn_s_sleep(2);
        asm volatile("" ::: "memory");
    }
    __syncthreads();
    ++gencount;
}

// ---------- the fused persistent kernel ----------
// part layout: part[slot][b][j][col], slot in {0,1}, j = writer bx.
__global__ __launch_bounds__(THREADS, 4) void sk_fused(
        const float* __restrict__ C, const float* __restrict__ eps,
        uint4* __restrict__ K16, uint4* __restrict__ K8,
        float* __restrict__ part, unsigned* __restrict__ bar,
        float* __restrict__ out) {
    __shared__ float4 smc[4][N / 4];  // 16 KB column-partial combine
    __shared__ float vsh[N];          // 4 KB inverted colsum broadcast
    __shared__ float u_lds[RPB];
    const int t = threadIdx.x;
    const int lane = t & 63, w = t >> 6;
    const int bid = blockIdx.x;
    const int b = bid >> 4, bx = bid & 15;
    const int row0 = bx * RPB + w * 16;
    unsigned gencount = 0;

    // ---- Phase 0: build K16 + K8, iteration 1 (v = 1) ----
    {
        const float nie = -1.0f / eps[0];
        const float4* __restrict__ Cp =
            (const float4*)(C + ((size_t)b * N + row0) * N) + lane * 4;
        uint4* __restrict__ Kp16 = K16 + ((size_t)b * N + row0) * NU4 + lane * 2;
        uint4* __restrict__ Kp8  = K8  + ((size_t)b * N + row0) * NU4F8 + lane;

        float colacc[16];
        #pragma unroll
        for (int q = 0; q < 16; ++q) colacc[q] = 0.0f;

        float4 cur[4];
        #pragma unroll
        for (int q = 0; q < 4; ++q) cur[q] = Cp[q];

        #pragma unroll
        for (int i = 0; i < 16; ++i) {
            float4 nxt[4];
            if (i < 15) {
                #pragma unroll
                for (int q = 0; q < 4; ++q) nxt[q] = Cp[(i + 1) * (N / 4) + q];
            }
            float k[16];
            const float* cf = (const float*)cur;
            #pragma unroll
            for (int q = 0; q < 16; ++q) k[q] = __expf(cf[q] * nie);

            Kp16[(size_t)i * NU4]     = h8_pack(k);
            Kp16[(size_t)i * NU4 + 1] = h8_pack(k + 8);
            Kp8[(size_t)i * NU4F8]    = pack_fp8_16(k);

            float s = (((k[0] + k[1]) + (k[2] + k[3])) + ((k[4] + k[5]) + (k[6] + k[7])))
                    + (((k[8] + k[9]) + (k[10] + k[11])) + ((k[12] + k[13]) + (k[14] + k[15])));
            #pragma unroll
            for (int off = 32; off; off >>= 1) s += __shfl_xor(s, off, 64);
            const float ui = 1.0f / s;

            #pragma unroll
            for (int q = 0; q < 16; ++q) colacc[q] += k[q] * ui;

            if (i < 15) {
                #pragma unroll
                for (int q = 0; q < 4; ++q) cur[q] = nxt[q];
            }
        }

        #pragma unroll
        for (int q = 0; q < 4; ++q)
            smc[w][lane * 4 + q] = make_float4(colacc[4 * q], colacc[4 * q + 1],
                                               colacc[4 * q + 2], colacc[4 * q + 3]);
        __syncthreads();
        float4 s0 = smc[0][t], s1 = smc[1][t], s2 = smc[2][t], s3 = smc[3][t];
        float* pw = part + (((size_t)0 * BATCH + b) * BPB + bx) * N + 4 * t;
        cstore(pw + 0, (s0.x + s1.x) + (s2.x + s3.x));
        cstore(pw + 1, (s0.y + s1.y) + (s2.y + s3.y));
        cstore(pw + 2, (s0.z + s1.z) + (s2.z + s3.z));
        cstore(pw + 3, (s0.w + s1.w) + (s2.w + s3.w));
    }
    gbar(bar, gencount);

    // ---- Phases 1..18: fp8 iterations (overall iterations 2..19) ----
    const uint4* __restrict__ Kp8r = K8 + ((size_t)b * N + row0) * NU4F8 + lane;
    #pragma unroll 1
    for (int p = 1; p <= 18; ++p) {
        // reduce previous slot's 16 partials -> inverted v in vsh
        {
            const float* pb =
                part + (((size_t)((p - 1) & 1) * BATCH + b) * BPB) * N + 4 * t;
            float a0 = 0.f, a1 = 0.f, a2 = 0.f, a3 = 0.f;
            #pragma unroll
            for (int j = 0; j < BPB; ++j) {
                const float* pj = pb + (size_t)j * N;
                a0 += cload(pj + 0);
                a1 += cload(pj + 1);
                a2 += cload(pj + 2);
                a3 += cload(pj + 3);
            }
            vsh[4 * t + 0] = 1.0f / a0;
            vsh[4 * t + 1] = 1.0f / a1;
            vsh[4 * t + 2] = 1.0f / a2;
            vsh[4 * t + 3] = 1.0f / a3;
        }
        __syncthreads();
        float vv[16];
        #pragma unroll
        for (int e = 0; e < 16; ++e) vv[e] = vsh[lane * 16 + e];

        float colacc[16];
        #pragma unroll
        for (int q = 0; q < 16; ++q) colacc[q] = 0.0f;

        uint4 buf[4];
        #pragma unroll
        for (int q = 0; q < 4; ++q) buf[q] = Kp8r[(size_t)q * NU4F8];

        #pragma unroll
        for (int i = 0; i < 16; ++i) {
            uint4 nx;
            if (i < 12) nx = Kp8r[(size_t)(i + 4) * NU4F8];

            float k[16];
            unpack_fp8_16(buf[i & 3], k);

            float pa = (k[0] * vv[0] + k[1] * vv[1]) + (k[2] * vv[2] + k[3] * vv[3]);
            float pb = (k[4] * vv[4] + k[5] * vv[5]) + (k[6] * vv[6] + k[7] * vv[7]);
            float pc = (k[8] * vv[8] + k[9] * vv[9]) + (k[10] * vv[10] + k[11] * vv[11]);
            float pd = (k[12] * vv[12] + k[13] * vv[13]) + (k[14] * vv[14] + k[15] * vv[15]);
            float s = (pa + pb) + (pc + pd);

            #pragma unroll
            for (int off = 32; off; off >>= 1) s += __shfl_xor(s, off, 64);
            const float ui = 1.0f / s;

            #pragma unroll
            for (int q = 0; q < 16; ++q) colacc[q] += k[q] * ui;

            if (i < 12) buf[i & 3] = nx;
        }

        #pragma unroll
        for (int q = 0; q < 4; ++q)
            smc[w][lane * 4 + q] = make_float4(colacc[4 * q], colacc[4 * q + 1],
                                               colacc[4 * q + 2], colacc[4 * q + 3]);
        __syncthreads();
        float4 s0 = smc[0][t], s1 = smc[1][t], s2 = smc[2][t], s3 = smc[3][t];
        float* pw = part + (((size_t)(p & 1) * BATCH + b) * BPB + bx) * N + 4 * t;
        cstore(pw + 0, (s0.x + s1.x) + (s2.x + s3.x));
        cstore(pw + 1, (s0.y + s1.y) + (s2.y + s3.y));
        cstore(pw + 2, (s0.z + s1.z) + (s2.z + s3.z));
        cstore(pw + 3, (s0.w + s1.w) + (s2.w + s3.w));
        gbar(bar, gencount);
    }

    // ---- Phase 19: fp16 iteration 20 (u kept in LDS) ----
    {
        {
            const float* pb = part + (((size_t)0 * BATCH + b) * BPB) * N + 4 * t;
            float a0 = 0.f, a1 = 0.f, a2 = 0.f, a3 = 0.f;
            #pragma unroll
            for (int j = 0; j < BPB; ++j) {
                const float* pj = pb + (size_t)j * N;
                a0 += cload(pj + 0);
                a1 += cload(pj + 1);
                a2 += cload(pj + 2);
                a3 += cload(pj + 3);
            }
            vsh[4 * t + 0] = 1.0f / a0;
            vsh[4 * t + 1] = 1.0f / a1;
            vsh[4 * t + 2] = 1.0f / a2;
            vsh[4 * t + 3] = 1.0f / a3;
        }
        __syncthreads();
        float vv[16];
        #pragma unroll
        for (int e = 0; e < 16; ++e) vv[e] = vsh[lane * 16 + e];

        const uint4* __restrict__ Kp = K16 + ((size_t)b * N + row0) * NU4 + lane * 2;

        float colacc[16];
        #pragma unroll
        for (int q = 0; q < 16; ++q) colacc[q] = 0.0f;

        uint4 c0 = Kp[0], c1 = Kp[1];
        #pragma unroll
        for (int i = 0; i < 16; ++i) {
            uint4 n0, n1;
            if (i < 15) {
                n0 = Kp[(size_t)(i + 1) * NU4];
                n1 = Kp[(size_t)(i + 1) * NU4 + 1];
            }
            float k[16];
            h8_unpack(c0, k);
            h8_unpack(c1, k + 8);

            float pa = (k[0] * vv[0] + k[1] * vv[1]) + (k[2] * vv[2] + k[3] * vv[3]);
            float pb = (k[4] * vv[4] + k[5] * vv[5]) + (k[6] * vv[6] + k[7] * vv[7]);
            float pc = (k[8] * vv[8] + k[9] * vv[9]) + (k[10] * vv[10] + k[11] * vv[11]);
            float pd = (k[12] * vv[12] + k[13] * vv[13]) + (k[14] * vv[14] + k[15] * vv[15]);
            float s = (pa + pb) + (pc + pd);

            #pragma unroll
            for (int off = 32; off; off >>= 1) s += __shfl_xor(s, off, 64);
            const float ui = 1.0f / s;
            if (lane == 0) u_lds[w * 16 + i] = ui;

            #pragma unroll
            for (int q = 0; q < 16; ++q) colacc[q] += k[q] * ui;

            if (i < 15) { c0 = n0; c1 = n1; }
        }

        #pragma unroll
        for (int q = 0; q < 4; ++q)
            smc[w][lane * 4 + q] = make_float4(colacc[4 * q], colacc[4 * q + 1],
                                               colacc[4 * q + 2], colacc[4 * q + 3]);
        __syncthreads();
        float4 s0 = smc[0][t], s1 = smc[1][t], s2 = smc[2][t], s3 = smc[3][t];
        float* pw = part + (((size_t)1 * BATCH + b) * BPB + bx) * N + 4 * t;
        cstore(pw + 0, (s0.x + s1.x) + (s2.x + s3.x));
        cstore(pw + 1, (s0.y + s1.y) + (s2.y + s3.y));
        cstore(pw + 2, (s0.z + s1.z) + (s2.z + s3.z));
        cstore(pw + 3, (s0.w + s1.w) + (s2.w + s3.w));
    }
    gbar(bar, gencount);

    // ---- Phase 20: final product, coalesced thread-per-float4 ----
    {
        {
            const float* pb = part + (((size_t)1 * BATCH + b) * BPB) * N + 4 * t;
            float a0 = 0.f, a1 = 0.f, a2 = 0.f, a3 = 0.f;
            #pragma unroll
            for (int j = 0; j < BPB; ++j) {
                const float* pj = pb + (size_t)j * N;
                a0 += cload(pj + 0);
                a1 += cload(pj + 1);
                a2 += cload(pj + 2);
                a3 += cload(pj + 3);
            }
            vsh[4 * t + 0] = 1.0f / a0;
            vsh[4 * t + 1] = 1.0f / a1;
            vsh[4 * t + 2] = 1.0f / a2;
            vsh[4 * t + 3] = 1.0f / a3;
        }
        __syncthreads();
        const float4 vvf = make_float4(vsh[4 * t + 0], vsh[4 * t + 1],
                                       vsh[4 * t + 2], vsh[4 * t + 3]);
        const size_t rowbase = (size_t)b * N + (size_t)bx * RPB;
        const uint2* __restrict__ K2 = (const uint2*)K16;

        uint2 kc = K2[rowbase * NU2 + t];
        for (int r = 0; r < RPB; ++r) {
            uint2 kn;
            if (r < RPB - 1) kn = K2[(rowbase + r + 1) * NU2 + t];
            const float ur = u_lds[r];
            float4 k = h4_to_f4(kc);
            float4 o;
            o.x = k.x * ur * vvf.x;
            o.y = k.y * ur * vvf.y;
            o.z = k.z * ur * vvf.z;
            o.w = k.w * ur * vvf.w;
            ((float4*)(out + (rowbase + r) * N))[t] = o;
            kc = kn;
        }
    }
}

// ---------- round-2 multi-kernel fallback (known-good) ----------

__global__ __launch_bounds__(THREADS) void sk_build(
        const float* __restrict__ C, const float* __restrict__ eps,
        uint4* __restrict__ K16, uint4* __restrict__ K8,
        float* __restrict__ u, float* __restrict__ csum_out) {
    __shared__ float4 smc[4][N / 4];
    const int t = threadIdx.x;
    const int lane = t & 63, w = t >> 6;
    const int b = blockIdx.y;
    const int row0 = blockIdx.x * RPB + w * 16;
    const float nie = -1.0f / eps[0];

    const float4* __restrict__ Cp =
        (const float4*)(C + ((size_t)b * N + row0) * N) + lane * 4;
    uint4* __restrict__ Kp16 = K16 + ((size_t)b * N + row0) * NU4 + lane * 2;
    uint4* __restrict__ Kp8  = K8  + ((size_t)b * N + row0) * NU4F8 + lane;

    float colacc[16];
    #pragma unroll
    for (int q = 0; q < 16; ++q) colacc[q] = 0.0f;

    float4 cur[4];
    #pragma unroll
    for (int q = 0; q < 4; ++q) cur[q] = Cp[q];

    for (int i = 0; i < 16; ++i) {
        float4 nxt[4];
        if (i < 15) {
            #pragma unroll
            for (int q = 0; q < 4; ++q) nxt[q] = Cp[(i + 1) * (N / 4) + q];
        }
        float k[16];
        const float* cf = (const float*)cur;
        #pragma unroll
        for (int q = 0; q < 16; ++q) k[q] = __expf(cf[q] * nie);

        Kp16[(size_t)i * NU4]     = h8_pack(k);
        Kp16[(size_t)i * NU4 + 1] = h8_pack(k + 8);
        Kp8[(size_t)i * NU4F8]    = pack_fp8_16(k);

        float s = (((k[0] + k[1]) + (k[2] + k[3])) + ((k[4] + k[5]) + (k[6] + k[7])))
                + (((k[8] + k[9]) + (k[10] + k[11])) + ((k[12] + k[13]) + (k[14] + k[15])));
        #pragma unroll
        for (int off = 32; off; off >>= 1) s += __shfl_xor(s, off, 64);
        const float ui = 1.0f / s;
        if (lane == 0) u[b * N + row0 + i] = ui;

        #pragma unroll
        for (int q = 0; q < 16; ++q) colacc[q] += k[q] * ui;

        if (i < 15) {
            #pragma unroll
            for (int q = 0; q < 4; ++q) cur[q] = nxt[q];
        }
    }

    #pragma unroll
    for (int q = 0; q < 4; ++q)
        smc[w][lane * 4 + q] = make_float4(colacc[4 * q], colacc[4 * q + 1],
                                           colacc[4 * q + 2], colacc[4 * q + 3]);
    __syncthreads();
    float4 s0 = smc[0][t], s1 = smc[1][t], s2 = smc[2][t], s3 = smc[3][t];
    float* cs = csum_out + b * N + 4 * t;
    atomicAdd(cs + 0, (s0.x + s1.x) + (s2.x + s3.x));
    atomicAdd(cs + 1, (s0.y + s1.y) + (s2.y + s3.y));
    atomicAdd(cs + 2, (s0.z + s1.z) + (s2.z + s3.z));
    atomicAdd(cs + 3, (s0.w + s1.w) + (s2.w + s3.w));
}

__global__ __launch_bounds__(THREADS) void sk_iter8(
        const uint4* __restrict__ K8, const float* __restrict__ csum_in,
        float* __restrict__ csum_out) {
    __shared__ float4 smc[4][N / 4];
    const int t = threadIdx.x;
    const int lane = t & 63, w = t >> 6;
    const int b = blockIdx.y;
    const int row0 = blockIdx.x * RPB + w * 16;

    const float4* __restrict__ cin = (const float4*)(csum_in + b * N) + lane * 4;
    float vv[16];
    #pragma unroll
    for (int q = 0; q < 4; ++q) {
        float4 c = cin[q];
        vv[4 * q + 0] = 1.0f / c.x;
        vv[4 * q + 1] = 1.0f / c.y;
        vv[4 * q + 2] = 1.0f / c.z;
        vv[4 * q + 3] = 1.0f / c.w;
    }

    const uint4* __restrict__ Kp = K8 + ((size_t)b * N + row0) * NU4F8 + lane;

    float colacc[16];
    #pragma unroll
    for (int q = 0; q < 16; ++q) colacc[q] = 0.0f;

    uint4 c0 = Kp[0];
    uint4 c1 = Kp[NU4F8];
    for (int i = 0; i < 16; ++i) {
        uint4 c2;
        if (i < 14) c2 = Kp[(size_t)(i + 2) * NU4F8];

        float k[16];
        unpack_fp8_16(c0, k);

        float pa = (k[0] * vv[0] + k[1] * vv[1]) + (k[2] * vv[2] + k[3] * vv[3]);
        float pb = (k[4] * vv[4] + k[5] * vv[5]) + (k[6] * vv[6] + k[7] * vv[7]);
        float pc = (k[8] * vv[8] + k[9] * vv[9]) + (k[10] * vv[10] + k[11] * vv[11]);
        float pd = (k[12] * vv[12] + k[13] * vv[13]) + (k[14] * vv[14] + k[15] * vv[15]);
        float s = (pa + pb) + (pc + pd);

        #pragma unroll
        for (int off = 32; off; off >>= 1) s += __shfl_xor(s, off, 64);
        const float ui = 1.0f / s;

        #pragma unroll
        for (int q = 0; q < 16; ++q) colacc[q] += k[q] * ui;

        c0 = c1;
        if (i < 14) c1 = c2;
    }

    #pragma unroll
    for (int q = 0; q < 4; ++q)
        smc[w][lane * 4 + q] = make_float4(colacc[4 * q], colacc[4 * q + 1],
                                           colacc[4 * q + 2], colacc[4 * q + 3]);
    __syncthreads();
    float4 s0 = smc[0][t], s1 = smc[1][t], s2 = smc[2][t], s3 = smc[3][t];
    float* cs = csum_out + b * N + 4 * t;
    atomicAdd(cs + 0, (s0.x + s1.x) + (s2.x + s3.x));
    atomicAdd(cs + 1, (s0.y + s1.y) + (s2.y + s3.y));
    atomicAdd(cs + 2, (s0.z + s1.z) + (s2.z + s3.z));
    atomicAdd(cs + 3, (s0.w + s1.w) + (s2.w + s3.w));
}

__global__ __launch_bounds__(THREADS) void sk_iter(
        const uint4* __restrict__ K, const float* __restrict__ csum_in,
        float* __restrict__ u, float* __restrict__ csum_out) {
    __shared__ float4 smc[4][N / 4];
    const int t = threadIdx.x;
    const int lane = t & 63, w = t >> 6;
    const int b = blockIdx.y;
    const int row0 = blockIdx.x * RPB + w * 16;

    const float4* __restrict__ cin = (const float4*)(csum_in + b * N) + lane * 4;
    float vv[16];
    #pragma unroll
    for (int q = 0; q < 4; ++q) {
        float4 c = cin[q];
        vv[4 * q + 0] = 1.0f / c.x;
        vv[4 * q + 1] = 1.0f / c.y;
        vv[4 * q + 2] = 1.0f / c.z;
        vv[4 * q + 3] = 1.0f / c.w;
    }

    const uint4* __restrict__ Kp = K + ((size_t)b * N + row0) * NU4 + lane * 2;

    float colacc[16];
    #pragma unroll
    for (int q = 0; q < 16; ++q) colacc[q] = 0.0f;

    uint4 c0 = Kp[0], c1 = Kp[1];
    for (int i = 0; i < 16; ++i) {
        uint4 n0, n1;
        if (i < 15) {
            n0 = Kp[(size_t)(i + 1) * NU4];
            n1 = Kp[(size_t)(i + 1) * NU4 + 1];
        }
        float k[16];
        h8_unpack(c0, k);
        h8_unpack(c1, k + 8);

        float pa = (k[0] * vv[0] + k[1] * vv[1]) + (k[2] * vv[2] + k[3] * vv[3]);
        float pb = (k[4] * vv[4] + k[5] * vv[5]) + (k[6] * vv[6] + k[7] * vv[7]);
        float pc = (k[8] * vv[8] + k[9] * vv[9]) + (k[10] * vv[10] + k[11] * vv[11]);
        float pd = (k[12] * vv[12] + k[13] * vv[13]) + (k[14] * vv[14] + k[15] * vv[15]);
        float s = (pa + pb) + (pc + pd);

        #pragma unroll
        for (int off = 32; off; off >>= 1) s += __shfl_xor(s, off, 64);
        const float ui = 1.0f / s;
        if (lane == 0) u[b * N + row0 + i] = ui;

        #pragma unroll
        for (int q = 0; q < 16; ++q) colacc[q] += k[q] * ui;

        if (i < 15) { c0 = n0; c1 = n1; }
    }

    #pragma unroll
    for (int q = 0; q < 4; ++q)
        smc[w][lane * 4 + q] = make_float4(colacc[4 * q], colacc[4 * q + 1],
                                           colacc[4 * q + 2], colacc[4 * q + 3]);
    __syncthreads();
    float4 s0 = smc[0][t], s1 = smc[1][t], s2 = smc[2][t], s3 = smc[3][t];
    float* cs = csum_out + b * N + 4 * t;
    atomicAdd(cs + 0, (s0.x + s1.x) + (s2.x + s3.x));
    atomicAdd(cs + 1, (s0.y + s1.y) + (s2.y + s3.y));
    atomicAdd(cs + 2, (s0.z + s1.z) + (s2.z + s3.z));
    atomicAdd(cs + 3, (s0.w + s1.w) + (s2.w + s3.w));
}

__global__ __launch_bounds__(THREADS) void sk_final(
        const uint2* __restrict__ K, const float* __restrict__ u,
        const float* __restrict__ csum_last, float* __restrict__ out) {
    const int t = threadIdx.x;
    const int row = blockIdx.x;
    const int b = blockIdx.y;
    const float ui = u[b * N + row];
    const float4 ci = ((const float4*)(csum_last + b * N))[t];
    const float4 vv = make_float4(1.0f / ci.x, 1.0f / ci.y, 1.0f / ci.z, 1.0f / ci.w);
    const size_t base = (size_t)b * N + row;
    float4 k = h4_to_f4((K + base * NU2)[t]);
    float4 o;
    o.x = k.x * ui * vv.x;
    o.y = k.y * ui * vv.y;
    o.z = k.z * ui * vv.z;
    o.w = k.w * ui * vv.w;
    ((float4*)(out + base * N))[t] = o;
}

// ---------- fallback all-fp32 path ----------

__device__ __forceinline__ float block_reduce_broadcast(float val, float* lds) {
    #pragma unroll
    for (int off = 32; off > 0; off >>= 1)
        val += __shfl_xor(val, off, 64);
    const int lane = threadIdx.x & 63;
    const int wid  = threadIdx.x >> 6;
    if (lane == 0) lds[wid] = val;
    __syncthreads();
    float total = lds[0] + lds[1] + lds[2] + lds[3];
    __syncthreads();
    return total;
}

__global__ __launch_bounds__(THREADS) void sink_init(float* __restrict__ v,
                                                     float* __restrict__ colsum) {
    const int i = blockIdx.x * THREADS + threadIdx.x;
    v[i] = 1.0f;
    colsum[i] = 0.0f;
}

__global__ __launch_bounds__(THREADS) void sink_iter(
        const float* __restrict__ C, const float* __restrict__ eps,
        const float* __restrict__ v, float* __restrict__ u,
        float* __restrict__ colsum) {
    __shared__ float lds[4];
    const int t = threadIdx.x;
    const int b = blockIdx.y;
    const int row0 = blockIdx.x * RPB;
    const float neg_inv_eps = -1.0f / eps[0];

    const float4 vv = ((const float4*)(v + b * N))[t];
    const float4* __restrict__ Cp = (const float4*)(C + ((size_t)b * N + row0) * N);

    float4 colacc = make_float4(0.f, 0.f, 0.f, 0.f);
    float4 cur = Cp[t];
    for (int i = 0; i < RPB; ++i) {
        float4 nxt = cur;
        if (i + 1 < RPB)
            nxt = Cp[(size_t)(i + 1) * (N / 4) + t];

        float4 k;
        k.x = __expf(cur.x * neg_inv_eps);
        k.y = __expf(cur.y * neg_inv_eps);
        k.z = __expf(cur.z * neg_inv_eps);
        k.w = __expf(cur.w * neg_inv_eps);

        float s = k.x * vv.x + k.y * vv.y + k.z * vv.z + k.w * vv.w;
        float S = block_reduce_broadcast(s, lds);
        float ui = 1.0f / S;
        if (t == 0) u[b * N + row0 + i] = ui;

        colacc.x += k.x * ui;
        colacc.y += k.y * ui;
        colacc.z += k.z * ui;
        colacc.w += k.w * ui;
        cur = nxt;
    }

    float* cs = colsum + b * N + 4 * t;
    atomicAdd(cs + 0, colacc.x);
    atomicAdd(cs + 1, colacc.y);
    atomicAdd(cs + 2, colacc.z);
    atomicAdd(cs + 3, colacc.w);
}

__global__ __launch_bounds__(THREADS) void sink_fix(float* __restrict__ v,
                                                    float* __restrict__ colsum) {
    const int i = blockIdx.x * THREADS + threadIdx.x;
    v[i] = 1.0f / colsum[i];
    colsum[i] = 0.0f;
}

__global__ __launch_bounds__(THREADS) void sink_final(
        const float* __restrict__ C, const float* __restrict__ eps,
        const float* __restrict__ u, const float* __restrict__ v,
        float* __restrict__ out) {
    const int t = threadIdx.x;
    const int row = blockIdx.x;
    const int b = blockIdx.y;
    const float neg_inv_eps = -1.0f / eps[0];
    const float ui = u[b * N + row];
    const float4 vv = ((const float4*)(v + b * N))[t];
    const size_t base = ((size_t)b * N + row) * N;
    float4 c = ((const float4*)(C + base))[t];
    float4 o;
    o.x = __expf(c.x * neg_inv_eps) * ui * vv.x;
    o.y = __expf(c.y * neg_inv_eps) * ui * vv.y;
    o.z = __expf(c.z * neg_inv_eps) * ui * vv.z;
    o.w = __expf(c.w * neg_inv_eps) * ui * vv.w;
    ((float4*)(out + base))[t] = o;
}

// ---------- launch ----------

extern "C" void kernel_launch(void* const* d_in, const int* in_sizes, int n_in,
                              void* d_out, int out_size, void* d_ws, size_t ws_size,
                              hipStream_t stream) {
    const float* C   = (const float*)d_in[0];
    const float* eps = (const float*)d_in[1];
    float* out = (float*)d_out;

    const size_t k16_bytes  = (size_t)BATCH * N * N * 2;   // 134 MB
    const size_t k8_bytes   = (size_t)BATCH * N * N;       // 67 MB
    const size_t part_bytes = PART_ELEMS * 4;              // 8 MB
    const size_t uv_elems   = (size_t)BATCH * N;           // 64K floats
    const size_t needed     = k16_bytes + k8_bytes + part_bytes +
                              BAR_WORDS * 4 + uv_elems * 4 + CSUM_FB_ELEMS * 4;

    if (ws_size >= needed) {
        uint4* K16    = (uint4*)d_ws;
        uint4* K8     = (uint4*)((char*)d_ws + k16_bytes);
        float* part   = (float*)((char*)d_ws + k16_bytes + k8_bytes);
        unsigned* bar = (unsigned*)(part + PART_ELEMS);
        float* u      = (float*)(bar + BAR_WORDS);         // fallback only
        float* csum   = u + uv_elems;                      // fallback only

        // co-residency check for the persistent kernel (cached)
        static int coop_ok = -1;
        if (coop_ok < 0) {
            int nb = 0;
            hipError_t e = hipOccupancyMaxActiveBlocksPerMultiprocessor(
                &nb, sk_fused, THREADS, 0);
            coop_ok = (e == hipSuccess && nb >= 4) ? 1 : 0;
        }

        if (coop_ok) {
            // only the barrier words need zeroing (partials are overwritten)
            sk_zero<<<dim3(1), dim3(THREADS), 0, stream>>>((float*)bar, BAR_WORDS);
            sk_fused<<<dim3(NBLK), dim3(THREADS), 0, stream>>>(
                C, eps, K16, K8, part, bar, out);
        } else {
            const int zero_total = (int)CSUM_FB_ELEMS;
            sk_zero<<<dim3((zero_total + THREADS - 1) / THREADS), dim3(THREADS),
                      0, stream>>>(csum, zero_total);
            sk_build<<<dim3(BPB, BATCH), dim3(THREADS), 0, stream>>>(
                C, eps, K16, K8, u, csum);
            for (int it = 2; it <= NITERS - 1; ++it) {
                sk_iter8<<<dim3(BPB, BATCH), dim3(THREADS), 0, stream>>>(
                    K8, csum + (size_t)(it - 2) * uv_elems,
                    csum + (size_t)(it - 1) * uv_elems);
            }
            sk_iter<<<dim3(BPB, BATCH), dim3(THREADS), 0, stream>>>(
                K16, csum + (size_t)(NITERS - 2) * uv_elems, u,
                csum + (size_t)(NITERS - 1) * uv_elems);
            sk_final<<<dim3(N, BATCH), dim3(THREADS), 0, stream>>>(
                (const uint2*)K16, u, csum + (size_t)(NITERS - 1) * uv_elems, out);
        }
    } else {
        float* u      = (float*)d_ws;
        float* v      = u + uv_elems;
        float* colsum = v + uv_elems;
        sink_init<<<dim3(BATCH * N / THREADS), dim3(THREADS), 0, stream>>>(v, colsum);
        for (int it = 0; it < NITERS; ++it) {
            sink_iter<<<dim3(BPB, BATCH), dim3(THREADS), 0, stream>>>(
                C, eps, v, u, colsum);
            sink_fix<<<dim3(BATCH * N / THREADS), dim3(THREADS), 0, stream>>>(v, colsum);
        }
        sink_final<<<dim3(N, BATCH), dim3(THREADS), 0, stream>>>(C, eps, u, v, out);
    }
}

// Round 5
// 1010.350 us; speedup vs baseline: 1.0081x; 1.0081x over previous
//
#include <hip/hip_runtime.h>
#include <hip/hip_fp16.h>

// Sinkhorn, 64 x 1024 x 1024 fp32, 20 iterations.
//
// K = exp(-C/eps); u = 1/(K v); v = 1/(K^T u); out = u_i K_ij v_j.
//
// Evidence through round 4: real (non-profiled) kernel time tracks TOTAL
// L2-miss bytes at ~6.3 TB/s. Base algorithm traffic is ~2 GB; the other
// ~4-6 GB was coherence-point amplification from device-scope csum
// atomics (R1-R3) / bulk agent-scope coherent loads (R4). This round cuts
// coherent traffic ~15x:
//  - per-BATCH barriers (16 blocks each), not a 1024-block global barrier
//  - last-arriver reduction: the block whose arrive-add returns 15 reads
//    the 16 x 4 KB partials, computes INVERTED v, cstores 4 KB, bumps the
//    batch generation; the 15 others poll and read only 4 KB of v
//  - v broadcast through stride-17 padded LDS (kills R4's 32-way bank
//    conflict on vsh[lane*16+e])
// Phase structure unchanged: build(K16+K8, iter1) -> 18 fp8 sweeps ->
// fp16 iter 20 -> final product from K16.
// Falls back to the round-2 multi-kernel path if occupancy check fails,
// and to the all-fp32 path if ws is too small.

#define BATCH 64
#define N 1024
#define NITERS 20
#define RPB 64                   // rows per block
#define BPB 16                   // blocks per batch
#define NBLK (BATCH * BPB)       // 1024 blocks
#define THREADS 256
#define NU2 (N / 4)              // uint2 (4 halves) per fp16 row
#define NU4 (N / 8)              // uint4 (8 halves) per fp16 row
#define NU4F8 (N / 16)           // uint4 (16 fp8) per fp8 row
#define VSH_STRIDE 17            // padded LDS stride for v broadcast
#define BAR_STRIDE 32            // uints per batch control block (cacheline)
#define PART_ELEMS ((size_t)BATCH * BPB * N)       // partials, one slot
#define VBUF_ELEMS ((size_t)BATCH * N)             // inverted colsums
#define BAR_WORDS (BATCH * BAR_STRIDE)             // arrive+gen per batch
#define CSUM_FB_ELEMS ((size_t)NITERS * BATCH * N) // fallback path only

typedef float f32x2 __attribute__((ext_vector_type(2)));

// ---------- fp16 pack/unpack helpers ----------
union H2U { __half2 h; unsigned u; };

__device__ __forceinline__ float4 h4_to_f4(uint2 r) {
    H2U a, b;
    a.u = r.x; b.u = r.y;
    float2 fa = __half22float2(a.h);
    float2 fb = __half22float2(b.h);
    return make_float4(fa.x, fa.y, fb.x, fb.y);
}

__device__ __forceinline__ void h8_unpack(uint4 r, float* f) {
    H2U a, b, c, d;
    a.u = r.x; b.u = r.y; c.u = r.z; d.u = r.w;
    float2 fa = __half22float2(a.h), fb = __half22float2(b.h);
    float2 fc = __half22float2(c.h), fd = __half22float2(d.h);
    f[0] = fa.x; f[1] = fa.y; f[2] = fb.x; f[3] = fb.y;
    f[4] = fc.x; f[5] = fc.y; f[6] = fd.x; f[7] = fd.y;
}

__device__ __forceinline__ uint4 h8_pack(const float* f) {
    H2U a, b, c, d;
    a.h = __float22half2_rn(make_float2(f[0], f[1]));
    b.h = __float22half2_rn(make_float2(f[2], f[3]));
    c.h = __float22half2_rn(make_float2(f[4], f[5]));
    d.h = __float22half2_rn(make_float2(f[6], f[7]));
    uint4 r; r.x = a.u; r.y = b.u; r.z = c.u; r.w = d.u;
    return r;
}

// ---------- fp8 (OCP e4m3) pack/unpack via gfx950 HW cvt ----------
__device__ __forceinline__ uint4 pack_fp8_16(const float* k) {
    uint4 r;
    int a;
    a = __builtin_amdgcn_cvt_pk_fp8_f32(k[0],  k[1],  0, false);
    a = __builtin_amdgcn_cvt_pk_fp8_f32(k[2],  k[3],  a, true);
    r.x = (unsigned)a;
    a = __builtin_amdgcn_cvt_pk_fp8_f32(k[4],  k[5],  0, false);
    a = __builtin_amdgcn_cvt_pk_fp8_f32(k[6],  k[7],  a, true);
    r.y = (unsigned)a;
    a = __builtin_amdgcn_cvt_pk_fp8_f32(k[8],  k[9],  0, false);
    a = __builtin_amdgcn_cvt_pk_fp8_f32(k[10], k[11], a, true);
    r.z = (unsigned)a;
    a = __builtin_amdgcn_cvt_pk_fp8_f32(k[12], k[13], 0, false);
    a = __builtin_amdgcn_cvt_pk_fp8_f32(k[14], k[15], a, true);
    r.w = (unsigned)a;
    return r;
}

__device__ __forceinline__ void unpack_fp8_16(uint4 r, float* f) {
    f32x2 p;
    p = __builtin_amdgcn_cvt_pk_f32_fp8((int)r.x, false); f[0]  = p.x; f[1]  = p.y;
    p = __builtin_amdgcn_cvt_pk_f32_fp8((int)r.x, true);  f[2]  = p.x; f[3]  = p.y;
    p = __builtin_amdgcn_cvt_pk_f32_fp8((int)r.y, false); f[4]  = p.x; f[5]  = p.y;
    p = __builtin_amdgcn_cvt_pk_f32_fp8((int)r.y, true);  f[6]  = p.x; f[7]  = p.y;
    p = __builtin_amdgcn_cvt_pk_f32_fp8((int)r.z, false); f[8]  = p.x; f[9]  = p.y;
    p = __builtin_amdgcn_cvt_pk_f32_fp8((int)r.z, true);  f[10] = p.x; f[11] = p.y;
    p = __builtin_amdgcn_cvt_pk_f32_fp8((int)r.w, false); f[12] = p.x; f[13] = p.y;
    p = __builtin_amdgcn_cvt_pk_f32_fp8((int)r.w, true);  f[14] = p.x; f[15] = p.y;
}

// ---------- coherent (agent-scope) load/store ----------
__device__ __forceinline__ float cload(const float* p) {
    return __hip_atomic_load((float*)p, __ATOMIC_RELAXED, __HIP_MEMORY_SCOPE_AGENT);
}
__device__ __forceinline__ void cstore(float* p, float v) {
    __hip_atomic_store(p, v, __ATOMIC_RELAXED, __HIP_MEMORY_SCOPE_AGENT);
}
__device__ __forceinline__ unsigned cloadu(const unsigned* p) {
    return __hip_atomic_load((unsigned*)p, __ATOMIC_RELAXED, __HIP_MEMORY_SCOPE_AGENT);
}

// ---------- generic zero ----------
__global__ __launch_bounds__(THREADS) void sk_zero(float* __restrict__ buf,
                                                   int total) {
    const int i = blockIdx.x * THREADS + threadIdx.x;
    if (i < total) buf[i] = 0.0f;
}

// ---------- per-batch colsum exchange ----------
// Publishes this block's 1024 column partials (float4 per thread), syncs
// the batch's 16 blocks, and leaves INVERTED colsums in vshp (padded).
// The last arriver does the reduction; others poll the batch gen word.
__device__ __forceinline__ void colsum_exchange(
        float4 ps, float* __restrict__ partb, float* __restrict__ vb,
        unsigned* __restrict__ arrive, unsigned* __restrict__ gen,
        unsigned& gencount, float* __restrict__ vshp,
        unsigned* __restrict__ redf, int t, int bx) {
    float* pw = partb + (size_t)bx * N + 4 * t;
    cstore(pw + 0, ps.x);
    cstore(pw + 1, ps.y);
    cstore(pw + 2, ps.z);
    cstore(pw + 3, ps.w);
    __syncthreads();  // drains vmcnt: partials ack'd at coherence point
    if (t == 0) {
        *redf = (__hip_atomic_fetch_add(arrive, 1u, __ATOMIC_RELAXED,
                                        __HIP_MEMORY_SCOPE_AGENT) == BPB - 1u)
                    ? 1u : 0u;
    }
    __syncthreads();
    const bool reducer = (*redf != 0u);
    const int c0 = 4 * t;
    const int vbase = (c0 >> 4) * VSH_STRIDE + (c0 & 15);
    if (reducer) {
        // all 256 threads: reduce 16 partials for cols 4t..4t+3
        float a0 = 0.f, a1 = 0.f, a2 = 0.f, a3 = 0.f;
        const float* pr = partb + c0;
        #pragma unroll
        for (int j = 0; j < BPB; ++j) {
            const float* pj = pr + (size_t)j * N;
            a0 += cload(pj + 0);
            a1 += cload(pj + 1);
            a2 += cload(pj + 2);
            a3 += cload(pj + 3);
        }
        const float i0 = 1.0f / a0, i1 = 1.0f / a1;
        const float i2 = 1.0f / a2, i3 = 1.0f / a3;
        cstore(vb + c0 + 0, i0);
        cstore(vb + c0 + 1, i1);
        cstore(vb + c0 + 2, i2);
        cstore(vb + c0 + 3, i3);
        vshp[vbase + 0] = i0;
        vshp[vbase + 1] = i1;
        vshp[vbase + 2] = i2;
        vshp[vbase + 3] = i3;
        __syncthreads();  // drains v cstores
        if (t == 0) {
            __hip_atomic_store(arrive, 0u, __ATOMIC_RELAXED,
                               __HIP_MEMORY_SCOPE_AGENT);
            asm volatile("s_waitcnt vmcnt(0)" ::: "memory");
            __hip_atomic_fetch_add(gen, 1u, __ATOMIC_RELAXED,
                                   __HIP_MEMORY_SCOPE_AGENT);
        }
    }
    if (t == 0) {
        while (cloadu(gen) == gencount)
            __builtin_amdgcn_s_sleep(2);
    }
    __syncthreads();
    ++gencount;
    if (!reducer) {
        vshp[vbase + 0] = cload(vb + c0 + 0);
        vshp[vbase + 1] = cload(vb + c0 + 1);
        vshp[vbase + 2] = cload(vb + c0 + 2);
        vshp[vbase + 3] = cload(vb + c0 + 3);
    }
    __syncthreads();
}

// ---------- the fused persistent kernel ----------
__global__ __launch_bounds__(THREADS, 4) void sk_fused(
        const float* __restrict__ C, const float* __restrict__ eps,
        uint4* __restrict__ K16, uint4* __restrict__ K8,
        float* __restrict__ part, float* __restrict__ vbuf,
        unsigned* __restrict__ bar, float* __restrict__ out) {
    __shared__ float4 smc[4][N / 4];          // 16 KB column-partial combine
    __shared__ float vshp[64 * VSH_STRIDE];   // 4.25 KB padded v broadcast
    __shared__ float u_lds[RPB];
    __shared__ unsigned redf;
    const int t = threadIdx.x;
    const int lane = t & 63, w = t >> 6;
    const int bid = blockIdx.x;
    const int b = bid >> 4, bx = bid & 15;
    const int row0 = bx * RPB + w * 16;
    unsigned* arrive = bar + b * BAR_STRIDE;
    unsigned* gen    = arrive + 1;
    float* partb = part + (size_t)b * BPB * N;
    float* vb    = vbuf + (size_t)b * N;
    unsigned gencount = 0;

    // ---- Phase 0: build K16 + K8, iteration 1 (v = 1) ----
    {
        const float nie = -1.0f / eps[0];
        const float4* __restrict__ Cp =
            (const float4*)(C + ((size_t)b * N + row0) * N) + lane * 4;
        uint4* __restrict__ Kp16 = K16 + ((size_t)b * N + row0) * NU4 + lane * 2;
        uint4* __restrict__ Kp8  = K8  + ((size_t)b * N + row0) * NU4F8 + lane;

        float colacc[16];
        #pragma unroll
        for (int q = 0; q < 16; ++q) colacc[q] = 0.0f;

        float4 cur[4];
        #pragma unroll
        for (int q = 0; q < 4; ++q) cur[q] = Cp[q];

        #pragma unroll
        for (int i = 0; i < 16; ++i) {
            float4 nxt[4];
            if (i < 15) {
                #pragma unroll
                for (int q = 0; q < 4; ++q) nxt[q] = Cp[(i + 1) * (N / 4) + q];
            }
            float k[16];
            const float* cf = (const float*)cur;
            #pragma unroll
            for (int q = 0; q < 16; ++q) k[q] = __expf(cf[q] * nie);

            Kp16[(size_t)i * NU4]     = h8_pack(k);
            Kp16[(size_t)i * NU4 + 1] = h8_pack(k + 8);
            Kp8[(size_t)i * NU4F8]    = pack_fp8_16(k);

            float s = (((k[0] + k[1]) + (k[2] + k[3])) + ((k[4] + k[5]) + (k[6] + k[7])))
                    + (((k[8] + k[9]) + (k[10] + k[11])) + ((k[12] + k[13]) + (k[14] + k[15])));
            #pragma unroll
            for (int off = 32; off; off >>= 1) s += __shfl_xor(s, off, 64);
            const float ui = 1.0f / s;

            #pragma unroll
            for (int q = 0; q < 16; ++q) colacc[q] += k[q] * ui;

            if (i < 15) {
                #pragma unroll
                for (int q = 0; q < 4; ++q) cur[q] = nxt[q];
            }
        }

        #pragma unroll
        for (int q = 0; q < 4; ++q)
            smc[w][lane * 4 + q] = make_float4(colacc[4 * q], colacc[4 * q + 1],
                                               colacc[4 * q + 2], colacc[4 * q + 3]);
        __syncthreads();
        float4 s0 = smc[0][t], s1 = smc[1][t], s2 = smc[2][t], s3 = smc[3][t];
        float4 ps;
        ps.x = (s0.x + s1.x) + (s2.x + s3.x);
        ps.y = (s0.y + s1.y) + (s2.y + s3.y);
        ps.z = (s0.z + s1.z) + (s2.z + s3.z);
        ps.w = (s0.w + s1.w) + (s2.w + s3.w);
        colsum_exchange(ps, partb, vb, arrive, gen, gencount, vshp, &redf, t, bx);
    }

    // ---- Phases 1..18: fp8 iterations (overall iterations 2..19) ----
    const uint4* __restrict__ Kp8r = K8 + ((size_t)b * N + row0) * NU4F8 + lane;
    #pragma unroll 1
    for (int p = 1; p <= 18; ++p) {
        float vv[16];
        #pragma unroll
        for (int e = 0; e < 16; ++e) vv[e] = vshp[lane * VSH_STRIDE + e];

        float colacc[16];
        #pragma unroll
        for (int q = 0; q < 16; ++q) colacc[q] = 0.0f;

        uint4 buf[4];
        #pragma unroll
        for (int q = 0; q < 4; ++q) buf[q] = Kp8r[(size_t)q * NU4F8];

        #pragma unroll
        for (int i = 0; i < 16; ++i) {
            uint4 nx;
            if (i < 12) nx = Kp8r[(size_t)(i + 4) * NU4F8];

            float k[16];
            unpack_fp8_16(buf[i & 3], k);

            float pa = (k[0] * vv[0] + k[1] * vv[1]) + (k[2] * vv[2] + k[3] * vv[3]);
            float pb = (k[4] * vv[4] + k[5] * vv[5]) + (k[6] * vv[6] + k[7] * vv[7]);
            float pc = (k[8] * vv[8] + k[9] * vv[9]) + (k[10] * vv[10] + k[11] * vv[11]);
            float pd = (k[12] * vv[12] + k[13] * vv[13]) + (k[14] * vv[14] + k[15] * vv[15]);
            float s = (pa + pb) + (pc + pd);

            #pragma unroll
            for (int off = 32; off; off >>= 1) s += __shfl_xor(s, off, 64);
            const float ui = 1.0f / s;

            #pragma unroll
            for (int q = 0; q < 16; ++q) colacc[q] += k[q] * ui;

            if (i < 12) buf[i & 3] = nx;
        }

        #pragma unroll
        for (int q = 0; q < 4; ++q)
            smc[w][lane * 4 + q] = make_float4(colacc[4 * q], colacc[4 * q + 1],
                                               colacc[4 * q + 2], colacc[4 * q + 3]);
        __syncthreads();
        float4 s0 = smc[0][t], s1 = smc[1][t], s2 = smc[2][t], s3 = smc[3][t];
        float4 ps;
        ps.x = (s0.x + s1.x) + (s2.x + s3.x);
        ps.y = (s0.y + s1.y) + (s2.y + s3.y);
        ps.z = (s0.z + s1.z) + (s2.z + s3.z);
        ps.w = (s0.w + s1.w) + (s2.w + s3.w);
        colsum_exchange(ps, partb, vb, arrive, gen, gencount, vshp, &redf, t, bx);
    }

    // ---- Phase 19: fp16 iteration 20 (u kept in LDS) ----
    {
        float vv[16];
        #pragma unroll
        for (int e = 0; e < 16; ++e) vv[e] = vshp[lane * VSH_STRIDE + e];

        const uint4* __restrict__ Kp = K16 + ((size_t)b * N + row0) * NU4 + lane * 2;

        float colacc[16];
        #pragma unroll
        for (int q = 0; q < 16; ++q) colacc[q] = 0.0f;

        uint4 c0 = Kp[0], c1 = Kp[1];
        #pragma unroll
        for (int i = 0; i < 16; ++i) {
            uint4 n0, n1;
            if (i < 15) {
                n0 = Kp[(size_t)(i + 1) * NU4];
                n1 = Kp[(size_t)(i + 1) * NU4 + 1];
            }
            float k[16];
            h8_unpack(c0, k);
            h8_unpack(c1, k + 8);

            float pa = (k[0] * vv[0] + k[1] * vv[1]) + (k[2] * vv[2] + k[3] * vv[3]);
            float pb = (k[4] * vv[4] + k[5] * vv[5]) + (k[6] * vv[6] + k[7] * vv[7]);
            float pc = (k[8] * vv[8] + k[9] * vv[9]) + (k[10] * vv[10] + k[11] * vv[11]);
            float pd = (k[12] * vv[12] + k[13] * vv[13]) + (k[14] * vv[14] + k[15] * vv[15]);
            float s = (pa + pb) + (pc + pd);

            #pragma unroll
            for (int off = 32; off; off >>= 1) s += __shfl_xor(s, off, 64);
            const float ui = 1.0f / s;
            if (lane == 0) u_lds[w * 16 + i] = ui;

            #pragma unroll
            for (int q = 0; q < 16; ++q) colacc[q] += k[q] * ui;

            if (i < 15) { c0 = n0; c1 = n1; }
        }

        #pragma unroll
        for (int q = 0; q < 4; ++q)
            smc[w][lane * 4 + q] = make_float4(colacc[4 * q], colacc[4 * q + 1],
                                               colacc[4 * q + 2], colacc[4 * q + 3]);
        __syncthreads();
        float4 s0 = smc[0][t], s1 = smc[1][t], s2 = smc[2][t], s3 = smc[3][t];
        float4 ps;
        ps.x = (s0.x + s1.x) + (s2.x + s3.x);
        ps.y = (s0.y + s1.y) + (s2.y + s3.y);
        ps.z = (s0.z + s1.z) + (s2.z + s3.z);
        ps.w = (s0.w + s1.w) + (s2.w + s3.w);
        colsum_exchange(ps, partb, vb, arrive, gen, gencount, vshp, &redf, t, bx);
    }

    // ---- Phase 20: final product, coalesced thread-per-float4 ----
    {
        const int c0 = 4 * t;
        const int vbase = (c0 >> 4) * VSH_STRIDE + (c0 & 15);
        const float4 vvf = make_float4(vshp[vbase + 0], vshp[vbase + 1],
                                       vshp[vbase + 2], vshp[vbase + 3]);
        const size_t rowbase = (size_t)b * N + (size_t)bx * RPB;
        const uint2* __restrict__ K2 = (const uint2*)K16;

        uint2 kc = K2[rowbase * NU2 + t];
        for (int r = 0; r < RPB; ++r) {
            uint2 kn;
            if (r < RPB - 1) kn = K2[(rowbase + r + 1) * NU2 + t];
            const float ur = u_lds[r];
            float4 k = h4_to_f4(kc);
            float4 o;
            o.x = k.x * ur * vvf.x;
            o.y = k.y * ur * vvf.y;
            o.z = k.z * ur * vvf.z;
            o.w = k.w * ur * vvf.w;
            ((float4*)(out + (rowbase + r) * N))[t] = o;
            kc = kn;
        }
    }
}

// ---------- round-2 multi-kernel fallback (known-good) ----------

__global__ __launch_bounds__(THREADS) void sk_build(
        const float* __restrict__ C, const float* __restrict__ eps,
        uint4* __restrict__ K16, uint4* __restrict__ K8,
        float* __restrict__ u, float* __restrict__ csum_out) {
    __shared__ float4 smc[4][N / 4];
    const int t = threadIdx.x;
    const int lane = t & 63, w = t >> 6;
    const int b = blockIdx.y;
    const int row0 = blockIdx.x * RPB + w * 16;
    const float nie = -1.0f / eps[0];

    const float4* __restrict__ Cp =
        (const float4*)(C + ((size_t)b * N + row0) * N) + lane * 4;
    uint4* __restrict__ Kp16 = K16 + ((size_t)b * N + row0) * NU4 + lane * 2;
    uint4* __restrict__ Kp8  = K8  + ((size_t)b * N + row0) * NU4F8 + lane;

    float colacc[16];
    #pragma unroll
    for (int q = 0; q < 16; ++q) colacc[q] = 0.0f;

    float4 cur[4];
    #pragma unroll
    for (int q = 0; q < 4; ++q) cur[q] = Cp[q];

    for (int i = 0; i < 16; ++i) {
        float4 nxt[4];
        if (i < 15) {
            #pragma unroll
            for (int q = 0; q < 4; ++q) nxt[q] = Cp[(i + 1) * (N / 4) + q];
        }
        float k[16];
        const float* cf = (const float*)cur;
        #pragma unroll
        for (int q = 0; q < 16; ++q) k[q] = __expf(cf[q] * nie);

        Kp16[(size_t)i * NU4]     = h8_pack(k);
        Kp16[(size_t)i * NU4 + 1] = h8_pack(k + 8);
        Kp8[(size_t)i * NU4F8]    = pack_fp8_16(k);

        float s = (((k[0] + k[1]) + (k[2] + k[3])) + ((k[4] + k[5]) + (k[6] + k[7])))
                + (((k[8] + k[9]) + (k[10] + k[11])) + ((k[12] + k[13]) + (k[14] + k[15])));
        #pragma unroll
        for (int off = 32; off; off >>= 1) s += __shfl_xor(s, off, 64);
        const float ui = 1.0f / s;
        if (lane == 0) u[b * N + row0 + i] = ui;

        #pragma unroll
        for (int q = 0; q < 16; ++q) colacc[q] += k[q] * ui;

        if (i < 15) {
            #pragma unroll
            for (int q = 0; q < 4; ++q) cur[q] = nxt[q];
        }
    }

    #pragma unroll
    for (int q = 0; q < 4; ++q)
        smc[w][lane * 4 + q] = make_float4(colacc[4 * q], colacc[4 * q + 1],
                                           colacc[4 * q + 2], colacc[4 * q + 3]);
    __syncthreads();
    float4 s0 = smc[0][t], s1 = smc[1][t], s2 = smc[2][t], s3 = smc[3][t];
    float* cs = csum_out + b * N + 4 * t;
    atomicAdd(cs + 0, (s0.x + s1.x) + (s2.x + s3.x));
    atomicAdd(cs + 1, (s0.y + s1.y) + (s2.y + s3.y));
    atomicAdd(cs + 2, (s0.z + s1.z) + (s2.z + s3.z));
    atomicAdd(cs + 3, (s0.w + s1.w) + (s2.w + s3.w));
}

__global__ __launch_bounds__(THREADS) void sk_iter8(
        const uint4* __restrict__ K8, const float* __restrict__ csum_in,
        float* __restrict__ csum_out) {
    __shared__ float4 smc[4][N / 4];
    const int t = threadIdx.x;
    const int lane = t & 63, w = t >> 6;
    const int b = blockIdx.y;
    const int row0 = blockIdx.x * RPB + w * 16;

    const float4* __restrict__ cin = (const float4*)(csum_in + b * N) + lane * 4;
    float vv[16];
    #pragma unroll
    for (int q = 0; q < 4; ++q) {
        float4 c = cin[q];
        vv[4 * q + 0] = 1.0f / c.x;
        vv[4 * q + 1] = 1.0f / c.y;
        vv[4 * q + 2] = 1.0f / c.z;
        vv[4 * q + 3] = 1.0f / c.w;
    }

    const uint4* __restrict__ Kp = K8 + ((size_t)b * N + row0) * NU4F8 + lane;

    float colacc[16];
    #pragma unroll
    for (int q = 0; q < 16; ++q) colacc[q] = 0.0f;

    uint4 c0 = Kp[0];
    uint4 c1 = Kp[NU4F8];
    for (int i = 0; i < 16; ++i) {
        uint4 c2;
        if (i < 14) c2 = Kp[(size_t)(i + 2) * NU4F8];

        float k[16];
        unpack_fp8_16(c0, k);

        float pa = (k[0] * vv[0] + k[1] * vv[1]) + (k[2] * vv[2] + k[3] * vv[3]);
        float pb = (k[4] * vv[4] + k[5] * vv[5]) + (k[6] * vv[6] + k[7] * vv[7]);
        float pc = (k[8] * vv[8] + k[9] * vv[9]) + (k[10] * vv[10] + k[11] * vv[11]);
        float pd = (k[12] * vv[12] + k[13] * vv[13]) + (k[14] * vv[14] + k[15] * vv[15]);
        float s = (pa + pb) + (pc + pd);

        #pragma unroll
        for (int off = 32; off; off >>= 1) s += __shfl_xor(s, off, 64);
        const float ui = 1.0f / s;

        #pragma unroll
        for (int q = 0; q < 16; ++q) colacc[q] += k[q] * ui;

        c0 = c1;
        if (i < 14) c1 = c2;
    }

    #pragma unroll
    for (int q = 0; q < 4; ++q)
        smc[w][lane * 4 + q] = make_float4(colacc[4 * q], colacc[4 * q + 1],
                                           colacc[4 * q + 2], colacc[4 * q + 3]);
    __syncthreads();
    float4 s0 = smc[0][t], s1 = smc[1][t], s2 = smc[2][t], s3 = smc[3][t];
    float* cs = csum_out + b * N + 4 * t;
    atomicAdd(cs + 0, (s0.x + s1.x) + (s2.x + s3.x));
    atomicAdd(cs + 1, (s0.y + s1.y) + (s2.y + s3.y));
    atomicAdd(cs + 2, (s0.z + s1.z) + (s2.z + s3.z));
    atomicAdd(cs + 3, (s0.w + s1.w) + (s2.w + s3.w));
}

__global__ __launch_bounds__(THREADS) void sk_iter(
        const uint4* __restrict__ K, const float* __restrict__ csum_in,
        float* __restrict__ u, float* __restrict__ csum_out) {
    __shared__ float4 smc[4][N / 4];
    const int t = threadIdx.x;
    const int lane = t & 63, w = t >> 6;
    const int b = blockIdx.y;
    const int row0 = blockIdx.x * RPB + w * 16;

    const float4* __restrict__ cin = (const float4*)(csum_in + b * N) + lane * 4;
    float vv[16];
    #pragma unroll
    for (int q = 0; q < 4; ++q) {
        float4 c = cin[q];
        vv[4 * q + 0] = 1.0f / c.x;
        vv[4 * q + 1] = 1.0f / c.y;
        vv[4 * q + 2] = 1.0f / c.z;
        vv[4 * q + 3] = 1.0f / c.w;
    }

    const uint4* __restrict__ Kp = K + ((size_t)b * N + row0) * NU4 + lane * 2;

    float colacc[16];
    #pragma unroll
    for (int q = 0; q < 16; ++q) colacc[q] = 0.0f;

    uint4 c0 = Kp[0], c1 = Kp[1];
    for (int i = 0; i < 16; ++i) {
        uint4 n0, n1;
        if (i < 15) {
            n0 = Kp[(size_t)(i + 1) * NU4];
            n1 = Kp[(size_t)(i + 1) * NU4 + 1];
        }
        float k[16];
        h8_unpack(c0, k);
        h8_unpack(c1, k + 8);

        float pa = (k[0] * vv[0] + k[1] * vv[1]) + (k[2] * vv[2] + k[3] * vv[3]);
        float pb = (k[4] * vv[4] + k[5] * vv[5]) + (k[6] * vv[6] + k[7] * vv[7]);
        float pc = (k[8] * vv[8] + k[9] * vv[9]) + (k[10] * vv[10] + k[11] * vv[11]);
        float pd = (k[12] * vv[12] + k[13] * vv[13]) + (k[14] * vv[14] + k[15] * vv[15]);
        float s = (pa + pb) + (pc + pd);

        #pragma unroll
        for (int off = 32; off; off >>= 1) s += __shfl_xor(s, off, 64);
        const float ui = 1.0f / s;
        if (lane == 0) u[b * N + row0 + i] = ui;

        #pragma unroll
        for (int q = 0; q < 16; ++q) colacc[q] += k[q] * ui;

        if (i < 15) { c0 = n0; c1 = n1; }
    }

    #pragma unroll
    for (int q = 0; q < 4; ++q)
        smc[w][lane * 4 + q] = make_float4(colacc[4 * q], colacc[4 * q + 1],
                                           colacc[4 * q + 2], colacc[4 * q + 3]);
    __syncthreads();
    float4 s0 = smc[0][t], s1 = smc[1][t], s2 = smc[2][t], s3 = smc[3][t];
    float* cs = csum_out + b * N + 4 * t;
    atomicAdd(cs + 0, (s0.x + s1.x) + (s2.x + s3.x));
    atomicAdd(cs + 1, (s0.y + s1.y) + (s2.y + s3.y));
    atomicAdd(cs + 2, (s0.z + s1.z) + (s2.z + s3.z));
    atomicAdd(cs + 3, (s0.w + s1.w) + (s2.w + s3.w));
}

__global__ __launch_bounds__(THREADS) void sk_final(
        const uint2* __restrict__ K, const float* __restrict__ u,
        const float* __restrict__ csum_last, float* __restrict__ out) {
    const int t = threadIdx.x;
    const int row = blockIdx.x;
    const int b = blockIdx.y;
    const float ui = u[b * N + row];
    const float4 ci = ((const float4*)(csum_last + b * N))[t];
    const float4 vv = make_float4(1.0f / ci.x, 1.0f / ci.y, 1.0f / ci.z, 1.0f / ci.w);
    const size_t base = (size_t)b * N + row;
    float4 k = h4_to_f4((K + base * NU2)[t]);
    float4 o;
    o.x = k.x * ui * vv.x;
    o.y = k.y * ui * vv.y;
    o.z = k.z * ui * vv.z;
    o.w = k.w * ui * vv.w;
    ((float4*)(out + base * N))[t] = o;
}

// ---------- fallback all-fp32 path ----------

__device__ __forceinline__ float block_reduce_broadcast(float val, float* lds) {
    #pragma unroll
    for (int off = 32; off > 0; off >>= 1)
        val += __shfl_xor(val, off, 64);
    const int lane = threadIdx.x & 63;
    const int wid  = threadIdx.x >> 6;
    if (lane == 0) lds[wid] = val;
    __syncthreads();
    float total = lds[0] + lds[1] + lds[2] + lds[3];
    __syncthreads();
    return total;
}

__global__ __launch_bounds__(THREADS) void sink_init(float* __restrict__ v,
                                                     float* __restrict__ colsum) {
    const int i = blockIdx.x * THREADS + threadIdx.x;
    v[i] = 1.0f;
    colsum[i] = 0.0f;
}

__global__ __launch_bounds__(THREADS) void sink_iter(
        const float* __restrict__ C, const float* __restrict__ eps,
        const float* __restrict__ v, float* __restrict__ u,
        float* __restrict__ colsum) {
    __shared__ float lds[4];
    const int t = threadIdx.x;
    const int b = blockIdx.y;
    const int row0 = blockIdx.x * RPB;
    const float neg_inv_eps = -1.0f / eps[0];

    const float4 vv = ((const float4*)(v + b * N))[t];
    const float4* __restrict__ Cp = (const float4*)(C + ((size_t)b * N + row0) * N);

    float4 colacc = make_float4(0.f, 0.f, 0.f, 0.f);
    float4 cur = Cp[t];
    for (int i = 0; i < RPB; ++i) {
        float4 nxt = cur;
        if (i + 1 < RPB)
            nxt = Cp[(size_t)(i + 1) * (N / 4) + t];

        float4 k;
        k.x = __expf(cur.x * neg_inv_eps);
        k.y = __expf(cur.y * neg_inv_eps);
        k.z = __expf(cur.z * neg_inv_eps);
        k.w = __expf(cur.w * neg_inv_eps);

        float s = k.x * vv.x + k.y * vv.y + k.z * vv.z + k.w * vv.w;
        float S = block_reduce_broadcast(s, lds);
        float ui = 1.0f / S;
        if (t == 0) u[b * N + row0 + i] = ui;

        colacc.x += k.x * ui;
        colacc.y += k.y * ui;
        colacc.z += k.z * ui;
        colacc.w += k.w * ui;
        cur = nxt;
    }

    float* cs = colsum + b * N + 4 * t;
    atomicAdd(cs + 0, colacc.x);
    atomicAdd(cs + 1, colacc.y);
    atomicAdd(cs + 2, colacc.z);
    atomicAdd(cs + 3, colacc.w);
}

__global__ __launch_bounds__(THREADS) void sink_fix(float* __restrict__ v,
                                                    float* __restrict__ colsum) {
    const int i = blockIdx.x * THREADS + threadIdx.x;
    v[i] = 1.0f / colsum[i];
    colsum[i] = 0.0f;
}

__global__ __launch_bounds__(THREADS) void sink_final(
        const float* __restrict__ C, const float* __restrict__ eps,
        const float* __restrict__ u, const float* __restrict__ v,
        float* __restrict__ out) {
    const int t = threadIdx.x;
    const int row = blockIdx.x;
    const int b = blockIdx.y;
    const float neg_inv_eps = -1.0f / eps[0];
    const float ui = u[b * N + row];
    const float4 vv = ((const float4*)(v + b * N))[t];
    const size_t base = ((size_t)b * N + row) * N;
    float4 c = ((const float4*)(C + base))[t];
    float4 o;
    o.x = __expf(c.x * neg_inv_eps) * ui * vv.x;
    o.y = __expf(c.y * neg_inv_eps) * ui * vv.y;
    o.z = __expf(c.z * neg_inv_eps) * ui * vv.z;
    o.w = __expf(c.w * neg_inv_eps) * ui * vv.w;
    ((float4*)(out + base))[t] = o;
}

// ---------- launch ----------

extern "C" void kernel_launch(void* const* d_in, const int* in_sizes, int n_in,
                              void* d_out, int out_size, void* d_ws, size_t ws_size,
                              hipStream_t stream) {
    const float* C   = (const float*)d_in[0];
    const float* eps = (const float*)d_in[1];
    float* out = (float*)d_out;

    const size_t k16_bytes  = (size_t)BATCH * N * N * 2;   // 134 MB
    const size_t k8_bytes   = (size_t)BATCH * N * N;       // 67 MB
    const size_t part_bytes = PART_ELEMS * 4;              // 4 MB
    const size_t vbuf_bytes = VBUF_ELEMS * 4;              // 256 KB
    const size_t bar_bytes  = BAR_WORDS * 4;               // 8 KB
    const size_t uv_elems   = (size_t)BATCH * N;           // 64K floats
    const size_t needed     = k16_bytes + k8_bytes + part_bytes + vbuf_bytes +
                              bar_bytes + uv_elems * 4 + CSUM_FB_ELEMS * 4;

    if (ws_size >= needed) {
        uint4* K16    = (uint4*)d_ws;
        uint4* K8     = (uint4*)((char*)d_ws + k16_bytes);
        float* part   = (float*)((char*)d_ws + k16_bytes + k8_bytes);
        float* vbuf   = part + PART_ELEMS;
        unsigned* bar = (unsigned*)(vbuf + VBUF_ELEMS);
        float* u      = (float*)(bar + BAR_WORDS);         // fallback only
        float* csum   = u + uv_elems;                      // fallback only

        // co-residency check for the persistent kernel (cached)
        static int coop_ok = -1;
        if (coop_ok < 0) {
            int nb = 0;
            hipError_t e = hipOccupancyMaxActiveBlocksPerMultiprocessor(
                &nb, sk_fused, THREADS, 0);
            coop_ok = (e == hipSuccess && nb >= 4) ? 1 : 0;
        }

        if (coop_ok) {
            // only the per-batch barrier words need zeroing (ws is poisoned)
            sk_zero<<<dim3((BAR_WORDS + THREADS - 1) / THREADS), dim3(THREADS),
                      0, stream>>>((float*)bar, BAR_WORDS);
            sk_fused<<<dim3(NBLK), dim3(THREADS), 0, stream>>>(
                C, eps, K16, K8, part, vbuf, bar, out);
        } else {
            const int zero_total = (int)CSUM_FB_ELEMS;
            sk_zero<<<dim3((zero_total + THREADS - 1) / THREADS), dim3(THREADS),
                      0, stream>>>(csum, zero_total);
            sk_build<<<dim3(BPB, BATCH), dim3(THREADS), 0, stream>>>(
                C, eps, K16, K8, u, csum);
            for (int it = 2; it <= NITERS - 1; ++it) {
                sk_iter8<<<dim3(BPB, BATCH), dim3(THREADS), 0, stream>>>(
                    K8, csum + (size_t)(it - 2) * uv_elems,
                    csum + (size_t)(it - 1) * uv_elems);
            }
            sk_iter<<<dim3(BPB, BATCH), dim3(THREADS), 0, stream>>>(
                K16, csum + (size_t)(NITERS - 2) * uv_elems, u,
                csum + (size_t)(NITERS - 1) * uv_elems);
            sk_final<<<dim3(N, BATCH), dim3(THREADS), 0, stream>>>(
                (const uint2*)K16, u, csum + (size_t)(NITERS - 1) * uv_elems, out);
        }
    } else {
        float* u      = (float*)d_ws;
        float* v      = u + uv_elems;
        float* colsum = v + uv_elems;
        sink_init<<<dim3(BATCH * N / THREADS), dim3(THREADS), 0, stream>>>(v, colsum);
        for (int it = 0; it < NITERS; ++it) {
            sink_iter<<<dim3(BPB, BATCH), dim3(THREADS), 0, stream>>>(
                C, eps, v, u, colsum);
            sink_fix<<<dim3(BATCH * N / THREADS), dim3(THREADS), 0, stream>>>(v, colsum);
        }
        sink_final<<<dim3(N, BATCH), dim3(THREADS), 0, stream>>>(C, eps, u, v, out);
    }
}